// Round 11
// baseline (423.546 us; speedup 1.0000x reference)
//
#include <hip/hip_runtime.h>

typedef unsigned short u16;
typedef __bf16 bf16x8 __attribute__((ext_vector_type(8)));
typedef float f32x4 __attribute__((ext_vector_type(4)));

union B8 { uint4 u; bf16x8 v; };
union U8 { u16 s[8]; uint4 u; };

#define NQ 2048
#define NK 2048
#define ND 128

template<int C>
__device__ __forceinline__ float dppf(float x) {
  int v = __builtin_bit_cast(int, x);
  int r = __builtin_amdgcn_update_dpp(v, v, C, 0xF, 0xF, true);
  return __builtin_bit_cast(float, r);
}
__device__ __forceinline__ float rowmax16(float x) {
  x = fmaxf(x, dppf<0xB1>(x));   // quad_perm xor1
  x = fmaxf(x, dppf<0x4E>(x));   // quad_perm xor2
  x = fmaxf(x, dppf<0x141>(x));  // row_half_mirror
  x = fmaxf(x, dppf<0x140>(x));  // row_mirror
  return x;
}
__device__ __forceinline__ float rowsum16(float x) {
  x += dppf<0xB1>(x);
  x += dppf<0x4E>(x);
  x += dppf<0x141>(x);
  x += dppf<0x140>(x);
  return x;
}

__device__ __forceinline__ bf16x8 cvt8(float4 a, float4 b) {
  bf16x8 r;
  r[0] = (__bf16)a.x; r[1] = (__bf16)a.y; r[2] = (__bf16)a.z; r[3] = (__bf16)a.w;
  r[4] = (__bf16)b.x; r[5] = (__bf16)b.y; r[6] = (__bf16)b.z; r[7] = (__bf16)b.w;
  return r;
}

// async 16B/lane global->LDS copy; HW writes LDS at wave-uniform base + lane*16.
__device__ __forceinline__ void async16(const u16* g, u16* l) {
  __builtin_amdgcn_global_load_lds(
      (const __attribute__((address_space(1))) unsigned int*)g,
      (__attribute__((address_space(3))) unsigned int*)l, 16, 0, 0);
}

constexpr float CEXP = 0.08838834764831845f * 1.44269504088896340f; // log2e/sqrt(128)

// ---------- Prepass: fp32 K/V -> bf16 tile images in workspace (verified r6) ----------
//   K: (row,g8) at row*128 + ((g8 ^ (row&15))<<3)             [8192 u16 = 16 KB]
//   V (d-major): (d,kv) at d*64 + (((kv>>3)^(d&7))<<3)+(kv&7) [8192 u16 = 16 KB]
__global__ __launch_bounds__(256)
void prepack(const float* __restrict__ kg, const float* __restrict__ vg,
             u16* __restrict__ wk, u16* __restrict__ wvp)
{
  __shared__ __align__(16) u16 sVp[8192];
  const int bt  = blockIdx.x;             // 0..511 = b*32 + t
  const int tid = threadIdx.x;
  const int srow = tid >> 2, scq = tid & 3;
  const size_t rowoff = (size_t)((bt >> 5) * NK + (bt & 31) * 64 + srow) * ND + scq * 32;

  u16* kimg = wk + (size_t)bt * 8192;
  {
    const float* src = kg + rowoff;
    #pragma unroll
    for (int c = 0; c < 4; ++c) {
      B8 tt; tt.v = cvt8(*(const float4*)(src + c * 8), *(const float4*)(src + c * 8 + 4));
      *(uint4*)(&kimg[srow * 128 + (((scq * 4 + c) ^ (srow & 15)) << 3)]) = tt.u;
    }
  }
  {
    const float* src = vg + rowoff;
    #pragma unroll
    for (int c = 0; c < 4; ++c) {
      B8 x; x.v = cvt8(*(const float4*)(src + c * 8), *(const float4*)(src + c * 8 + 4));
      U8 tt; tt.u = x.u;
      #pragma unroll
      for (int j = 0; j < 8; ++j) {
        int d = scq * 32 + c * 8 + j;
        sVp[d * 64 + (((srow >> 3) ^ j) << 3) + (srow & 7)] = tt.s[j];
      }
    }
  }
  __syncthreads();
  u16* vimg = wvp + (size_t)bt * 8192;
  const uint4* s4 = (const uint4*)sVp;
  uint4* d4 = (uint4*)vimg;
  #pragma unroll
  for (int k = 0; k < 4; ++k) d4[tid + 256 * k] = s4[tid + 256 * k];
}

// ---------- flash_chunk3: task = (b, 128-row q-tile, 512-row KV chunk) ----------
// r8-exact compute config (measured 66us, perfectly load-balanced): 512 threads =
// 8 q-waves x 16 rows, double-buffered K/V via global_load_lds, LDS 80KB ->
// 2 blocks/CU (16 waves/CU). Deltas vs r8: launch_bounds(512,2) frees regalloc
// (r8's VGPR=64 showed ~8MB suspected spill in WRITE); s_setprio(1) around MFMA
// clusters (T5: phase diversity exists with 2 independent blocks/CU); nc==1 fast
// path; in-kernel LAST-finisher merge (r10-verified protocol, done[] memset ->
// old+1==nc), saving the 3rd dispatch.
__global__ __launch_bounds__(512, 2)
void flash_chunk3(const float* __restrict__ qg, const int* __restrict__ vlg,
                  const u16* __restrict__ wk, const u16* __restrict__ wvp,
                  float* __restrict__ pO, float* __restrict__ pML,
                  int* __restrict__ done, float* __restrict__ og)
{
  __shared__ __align__(16) u16 sK[2][8192];   // 32 KB
  __shared__ __align__(16) u16 sV[2][8192];   // 32 KB
  __shared__ __align__(16) u16 sP[8][1024];   // 16 KB (overlaid by wts/winflag post-loop)

  const int tid  = threadIdx.x;
  const int lane = tid & 63;
  const int wv   = tid >> 6;     // q-wave 0..7 (16 rows each)
  const int n    = lane & 15;
  const int quad = lane >> 4;

  const int bi   = blockIdx.x;   // 1024 blocks
  // XCD-swizzle: XCD x (= bi&7) serves batches {2x,2x+1} -> image L2 locality
  const int b    = ((bi & 7) << 1) | ((bi >> 3) & 1);
  const int qt   = (bi >> 4) & 15;
  const int ck   = bi >> 8;      // KV chunk 0..3 (8 tiles = 512 rows each)

  const int vl = vlg[b];
  const int nt = (vl + 63) >> 6;
  const int t0 = ck * 8;
  if (t0 >= nt) return;          // dead chunk: uniform exit, no barriers executed
  const int t1 = (t0 + 8 < nt) ? (t0 + 8) : nt;
  const int nc = (nt + 7) >> 3;  // live chunks for this (b,qt): 1..4

  const int qrow0 = qt * 128 + wv * 16;

  // Q fragments (A-layout: A[m=lane&15][k=quad*8+j])
  bf16x8 qf[4];
  #pragma unroll
  for (int c = 0; c < 4; ++c) {
    const float* qp = qg + (size_t)(b * NQ + qrow0 + n) * ND + c * 32 + quad * 8;
    qf[c] = cvt8(*(const float4*)qp, *(const float4*)(qp + 4));
  }

  f32x4 O[8];
  float mst[4], lst[4];
  #pragma unroll
  for (int f = 0; f < 8; ++f) O[f] = (f32x4){0.f, 0.f, 0.f, 0.f};
  #pragma unroll
  for (int r = 0; r < 4; ++r) { mst[r] = -__builtin_inff(); lst[r] = 0.f; }

  // Staging: 8 waves each async-copy their 1024-u16 slice of the K and V images.
  #define STAGE(t, buf)                                                        \
    do {                                                                       \
      const size_t io_ = (size_t)(b * 32 + (t)) * 8192 + wv * 1024;            \
      const u16* gk_ = wk  + io_ + lane * 8;                                   \
      const u16* gv_ = wvp + io_ + lane * 8;                                   \
      u16* lk_ = sK[(buf)] + wv * 1024 + lane * 8;                             \
      u16* lv_ = sV[(buf)] + wv * 1024 + lane * 8;                             \
      async16(gk_,       lk_);                                                 \
      async16(gk_ + 512, lk_ + 512);                                           \
      async16(gv_,       lv_);                                                 \
      async16(gv_ + 512, lv_ + 512);                                           \
    } while (0)

  u16* const Pw = sP[wv];

  STAGE(t0, 0);

  for (int t = t0; t < t1; ++t) {
    __syncthreads();                 // vmcnt(0) drain => buf((t-t0)&1) ready
    if (t + 1 < t1) STAGE(t + 1, (t - t0 + 1) & 1);

    const u16* Kg = sK[(t - t0) & 1];
    const u16* Vg = sV[(t - t0) & 1];

    // ---- S = Q * K^T  (16 MFMAs, 16 b128 reads) ----
    f32x4 S[4];
    #pragma unroll
    for (int jn = 0; jn < 4; ++jn) S[jn] = (f32x4){0.f, 0.f, 0.f, 0.f};
    __builtin_amdgcn_s_setprio(1);                 // T5: favor MFMA wave
    #pragma unroll
    for (int c = 0; c < 4; ++c)
      #pragma unroll
      for (int jn = 0; jn < 4; ++jn) {
        B8 bb;   // B-frag: K[col=jn*16+n][d=c*32+quad*8+j]
        bb.u = *(const uint4*)(&Kg[(jn * 16 + n) * 128 + (((c * 4 + quad) ^ n) << 3)]);
        S[jn] = __builtin_amdgcn_mfma_f32_16x16x32_bf16(qf[c], bb.v, S[jn], 0, 0, 0);
      }
    __builtin_amdgcn_s_setprio(0);

    // ---- mask tail columns (kv >= vl) ----
    if (t * 64 + 64 > vl) {
      #pragma unroll
      for (int jn = 0; jn < 4; ++jn) {
        const bool msk = (t * 64 + jn * 16 + n) >= vl;
        #pragma unroll
        for (int r = 0; r < 4; ++r)
          S[jn][r] = msk ? -1e30f : S[jn][r];
      }
    }

    // ---- online softmax (4 independent row-chains) ----
    float al[4];
    #pragma unroll
    for (int r = 0; r < 4; ++r) {
      float mx = fmaxf(fmaxf(S[0][r], S[1][r]), fmaxf(S[2][r], S[3][r]));
      mx = rowmax16(mx);
      float mnew = fmaxf(mst[r], mx);
      float a = __builtin_exp2f((mst[r] - mnew) * CEXP);
      mst[r] = mnew;
      float ssum = 0.f;
      #pragma unroll
      for (int jn = 0; jn < 4; ++jn) {
        float p = __builtin_exp2f((S[jn][r] - mnew) * CEXP);
        S[jn][r] = p;
        ssum += p;
      }
      ssum = rowsum16(ssum);
      lst[r] = lst[r] * a + ssum;
      al[r] = a;
    }
    #pragma unroll
    for (int f = 0; f < 8; ++f) {
      O[f][0] *= al[0]; O[f][1] *= al[1]; O[f][2] *= al[2]; O[f][3] *= al[3];
    }

    // P (C-layout) -> per-wave LDS; same-wave DS order guarantees RAW
    #pragma unroll
    for (int jn = 0; jn < 4; ++jn)
      #pragma unroll
      for (int r = 0; r < 4; ++r) {
        int row = quad * 4 + r;
        __bf16 h = (__bf16)S[jn][r];
        Pw[row * 64 + (((jn * 2 + (n >> 3)) ^ (row & 7)) << 3) + (n & 7)]
            = __builtin_bit_cast(u16, h);
      }

    // ---- O += P * V  (16 MFMAs, 2+16 b128 reads) ----
    __builtin_amdgcn_s_setprio(1);
    #pragma unroll
    for (int kc = 0; kc < 2; ++kc) {
      B8 ta;   // A-frag: P[m=n][k=kc*32+quad*8+j]
      ta.u = *(const uint4*)(&Pw[n * 64 + (((kc * 4 + quad) ^ (n & 7)) << 3)]);
      bf16x8 af = ta.v;
      #pragma unroll
      for (int f = 0; f < 8; ++f) {
        int d = f * 16 + n;                 // d&7 == n&7
        B8 bb;   // B-frag: V[k=kv][n=d] from d-major sV
        bb.u = *(const uint4*)(&Vg[d * 64 + (((kc * 4 + quad) ^ (n & 7)) << 3)]);
        O[f] = __builtin_amdgcn_mfma_f32_16x16x32_bf16(af, bb.v, O[f], 0, 0, 0);
      }
    }
    __builtin_amdgcn_s_setprio(0);
  }
  #undef STAGE

  // ---- epilogue ----
  if (nc == 1) {
    // single live chunk (vl <= 512): normalize in-register, store directly
    #pragma unroll
    for (int r = 0; r < 4; ++r) {
      const float rl = 1.0f / lst[r];
      const int qrow = qrow0 + quad * 4 + r;
      float* op = og + (size_t)(b * NQ + qrow) * ND + n;
      #pragma unroll
      for (int f = 0; f < 8; ++f)
        op[f * 16] = O[f][r] * rl;
    }
    return;
  }

  // write unnormalized partial O + (m,l)  (r8-verified layout)
  const size_t ti = (size_t)((b * 16 + qt) * 4 + ck);
  float* po = pO + ti * 16384;
  #pragma unroll
  for (int f = 0; f < 8; ++f)
    #pragma unroll
    for (int r = 0; r < 4; ++r)
      po[(wv * 16 + quad * 4 + r) * 128 + f * 16 + n] = O[f][r];
  if (n == 0) {
    float* ps = pML + ti * 256;
    #pragma unroll
    for (int r = 0; r < 4; ++r) {
      const int row = wv * 16 + quad * 4 + r;
      ps[row * 2]     = mst[r];
      ps[row * 2 + 1] = lst[r];
    }
  }

  // LAST-finisher merge (r10-verified protocol; done[] zeroed by memset/launch)
  float* const wts   = (float*)sP;          // 128 rows x 4 weights (2 KB)
  int*   const winfl = (int*)sP + 512;      // after wts

  __threadfence();                          // release: partials visible device-wide
  __syncthreads();                          // all threads' stores done before atomic
  if (tid == 0) {
    const int old = atomicAdd(&done[b * 16 + qt], 1);
    *winfl = (old + 1 == nc);
  }
  __syncthreads();
  if (!*winfl) return;
  __threadfence();                          // acquire: see other chunks' partials

  const size_t ti0 = (size_t)(b * 16 + qt) * 4;
  if (tid < 128) {
    const int row = tid;
    float m[4], l[4];
    float mx = -__builtin_inff();
    for (int c = 0; c < nc; ++c) {
      m[c] = pML[(ti0 + c) * 256 + row * 2];
      l[c] = pML[(ti0 + c) * 256 + row * 2 + 1];
      mx = fmaxf(mx, m[c]);
    }
    float L = 0.f;
    float a[4];
    for (int c = 0; c < nc; ++c) {
      a[c] = __builtin_exp2f((m[c] - mx) * CEXP);
      L += l[c] * a[c];
    }
    const float inv = 1.0f / L;
    #pragma unroll
    for (int c = 0; c < 4; ++c)
      wts[row * 4 + c] = (c < nc) ? a[c] * inv : 0.f;
  }
  __syncthreads();

  const float4* p4 = (const float4*)(pO + ti0 * 16384);
  float4* o4 = (float4*)(og + (size_t)(b * NQ + qt * 128) * ND);
  #pragma unroll
  for (int it = 0; it < 8; ++it) {
    const int gi  = it * 512 + tid;    // float4 index 0..4095
    const int row = gi >> 5;           // 32 float4 per row
    float4 acc = {0.f, 0.f, 0.f, 0.f};
    for (int c = 0; c < nc; ++c) {
      const float4 x = p4[c * 4096 + gi];
      const float s = wts[row * 4 + c];
      acc.x += x.x * s; acc.y += x.y * s; acc.z += x.z * s; acc.w += x.w * s;
    }
    o4[gi] = acc;
  }
}

// ---------- Fallback (ws < 82MB): reg-staging kernel, verified r6 ----------
__global__ __launch_bounds__(1024)
void flash_fwd_fb(const float* __restrict__ qg, const float* __restrict__ kg,
                  const float* __restrict__ vg, const int* __restrict__ vlg,
                  float* __restrict__ og)
{
  __shared__ __align__(16) u16 sK[2][64 * 128];
  __shared__ __align__(16) u16 sV[2][64 * 128];
  __shared__ __align__(16) u16 sP[16][16 * 64];

  const int tid  = threadIdx.x;
  const int lane = tid & 63;
  const int wv   = tid >> 6;
  const int qw   = wv & 7;
  const int grp  = wv >> 3;
  const int n    = lane & 15;
  const int quad = lane >> 4;

  const int bi = blockIdx.x;
  const int b  = ((bi & 7) << 1) | ((bi >> 3) & 1);
  const int qt = bi >> 4;

  const int vl = vlg[b];
  const int nt = (vl + 63) >> 6;
  const int qrow0 = qt * 128 + qw * 16;

  bf16x8 qf[4];
  #pragma unroll
  for (int c = 0; c < 4; ++c) {
    const float* qp = qg + (size_t)(b * NQ + qrow0 + n) * ND + c * 32 + quad * 8;
    qf[c] = cvt8(*(const float4*)qp, *(const float4*)(qp + 4));
  }

  f32x4 O[8];
  float mst[4], lst[4];
  #pragma unroll
  for (int f = 0; f < 8; ++f) O[f] = (f32x4){0.f, 0.f, 0.f, 0.f};
  #pragma unroll
  for (int r = 0; r < 4; ++r) { mst[r] = -__builtin_inff(); lst[r] = 0.f; }

  const float* kb = kg + (size_t)(b * NK) * ND;
  const float* vb = vg + (size_t)(b * NK) * ND;
  const int stid = tid & 511;
  const int srow = stid >> 3, sc8 = stid & 7;
  bf16x8 kreg[2], vreg[2];

  auto kload = [&](int t) {
    const float* src = kb + (size_t)(t * 64 + srow) * ND + sc8 * 16;
    #pragma unroll
    for (int c = 0; c < 2; ++c)
      kreg[c] = cvt8(*(const float4*)(src + c * 8), *(const float4*)(src + c * 8 + 4));
  };
  auto kstore = [&]() {
    #pragma unroll
    for (int c = 0; c < 2; ++c) {
      B8 tt; tt.v = kreg[c];
      *(uint4*)(&sK[grp][srow * 128 + (((sc8 * 2 + c) ^ (srow & 15)) << 3)]) = tt.u;
    }
  };
  auto vload = [&](int t) {
    const float* src = vb + (size_t)(t * 64 + srow) * ND + sc8 * 16;
    #pragma unroll
    for (int c = 0; c < 2; ++c)
      vreg[c] = cvt8(*(const float4*)(src + c * 8), *(const float4*)(src + c * 8 + 4));
  };
  auto vstore = [&]() {
    #pragma unroll
    for (int c = 0; c < 2; ++c) {
      B8 x; x.v = vreg[c];
      U8 tt; tt.u = x.u;
      #pragma unroll
      for (int j = 0; j < 8; ++j) {
        int d = sc8 * 16 + c * 8 + j;
        sV[grp][d * 64 + (((srow >> 3) ^ j) << 3) + (srow & 7)] = tt.s[j];
      }
    }
  };

  if (grp < nt) { kload(grp); vload(grp); kstore(); vstore(); }

  u16* Pw = sP[wv];
  const u16* Kg = sK[grp];
  const u16* Vg = sV[grp];

  const int NS = (nt + 1) >> 1;
  for (int i = 0; i < NS; ++i) {
    __syncthreads();
    const int t  = 2 * i + grp;
    const int tn = t + 2;
    if (tn < nt) { kload(tn); vload(tn); }

    if (t < nt) {
      f32x4 S[4];
      #pragma unroll
      for (int jn = 0; jn < 4; ++jn) S[jn] = (f32x4){0.f, 0.f, 0.f, 0.f};
      #pragma unroll
      for (int c = 0; c < 4; ++c)
        #pragma unroll
        for (int jn = 0; jn < 4; ++jn) {
          B8 bb;
          bb.u = *(const uint4*)(&Kg[(jn * 16 + n) * 128 + (((c * 4 + quad) ^ n) << 3)]);
          S[jn] = __builtin_amdgcn_mfma_f32_16x16x32_bf16(qf[c], bb.v, S[jn], 0, 0, 0);
        }
      if (t * 64 + 64 > vl) {
        #pragma unroll
        for (int jn = 0; jn < 4; ++jn) {
          const bool msk = (t * 64 + jn * 16 + n) >= vl;
          #pragma unroll
          for (int r = 0; r < 4; ++r)
            S[jn][r] = msk ? -1e30f : S[jn][r];
        }
      }
      float al[4];
      #pragma unroll
      for (int r = 0; r < 4; ++r) {
        float mx = fmaxf(fmaxf(S[0][r], S[1][r]), fmaxf(S[2][r], S[3][r]));
        mx = rowmax16(mx);
        float mnew = fmaxf(mst[r], mx);
        float a = __builtin_exp2f((mst[r] - mnew) * CEXP);
        mst[r] = mnew;
        float ssum = 0.f;
        #pragma unroll
        for (int jn = 0; jn < 4; ++jn) {
          float p = __builtin_exp2f((S[jn][r] - mnew) * CEXP);
          S[jn][r] = p;
          ssum += p;
        }
        ssum = rowsum16(ssum);
        lst[r] = lst[r] * a + ssum;
        al[r] = a;
      }
      #pragma unroll
      for (int f = 0; f < 8; ++f) {
        O[f][0] *= al[0]; O[f][1] *= al[1]; O[f][2] *= al[2]; O[f][3] *= al[3];
      }
      #pragma unroll
      for (int jn = 0; jn < 4; ++jn)
        #pragma unroll
        for (int r = 0; r < 4; ++r) {
          int row = quad * 4 + r;
          __bf16 h = (__bf16)S[jn][r];
          Pw[row * 64 + (((jn * 2 + (n >> 3)) ^ (row & 7)) << 3) + (n & 7)]
              = __builtin_bit_cast(u16, h);
        }
      #pragma unroll
      for (int kc = 0; kc < 2; ++kc) {
        B8 ta;
        ta.u = *(const uint4*)(&Pw[n * 64 + (((kc * 4 + quad) ^ (n & 7)) << 3)]);
        bf16x8 af = ta.v;
        #pragma unroll
        for (int f = 0; f < 8; ++f) {
          int d = f * 16 + n;
          B8 bb;
          bb.u = *(const uint4*)(&Vg[d * 64 + (((kc * 4 + quad) ^ (n & 7)) << 3)]);
          O[f] = __builtin_amdgcn_mfma_f32_16x16x32_bf16(af, bb.v, O[f], 0, 0, 0);
        }
      }
    }
    __syncthreads();
    if (tn < nt) { kstore(); vstore(); }
  }

  if (grp == 1) {
    float* ob = ((qw < 4) ? (float*)sK : (float*)sV) + (qw & 3) * 2048 + lane * 32;
    #pragma unroll
    for (int f = 0; f < 8; ++f)
      #pragma unroll
      for (int r = 0; r < 4; ++r)
        ob[f * 4 + r] = O[f][r];
    float* sb = (float*)sP + qw * 512 + lane * 8;
    #pragma unroll
    for (int r = 0; r < 4; ++r) { sb[r] = mst[r]; sb[4 + r] = lst[r]; }
  }
  __syncthreads();
  if (grp == 0) {
    const float* ob = ((qw < 4) ? (const float*)sK : (const float*)sV) + (qw & 3) * 2048 + lane * 32;
    const float* sb = (const float*)sP + qw * 512 + lane * 8;
    #pragma unroll
    for (int r = 0; r < 4; ++r) {
      const float m1 = sb[r], l1 = sb[4 + r];
      const float m  = fmaxf(mst[r], m1);
      const float a0 = __builtin_exp2f((mst[r] - m) * CEXP);
      const float a1 = __builtin_exp2f((m1 - m) * CEXP);
      const float rl = 1.0f / (lst[r] * a0 + l1 * a1);
      const int qrow = qrow0 + quad * 4 + r;
      float* op = og + (size_t)(b * NQ + qrow) * ND + n;
      #pragma unroll
      for (int f = 0; f < 8; ++f)
        op[f * 16] = (O[f][r] * a0 + ob[f * 4 + r] * a1) * rl;
    }
  }
}

extern "C" void kernel_launch(void* const* d_in, const int* in_sizes, int n_in,
                              void* d_out, int out_size, void* d_ws, size_t ws_size,
                              hipStream_t stream) {
  const float* q  = (const float*)d_in[0];
  const float* k  = (const float*)d_in[1];
  const float* v  = (const float*)d_in[2];
  const int*  vl  = (const int*)d_in[3];
  float* out = (float*)d_out;

  const size_t need_split = (size_t)82 * 1024 * 1024;   // images + partials + done

  if (ws_size >= need_split) {
    u16*   wk  = (u16*)d_ws;                                           // @0,  8MB
    u16*   wvv = wk + 4194304;                                         // @8MB, 8MB
    float* pO  = (float*)((char*)d_ws + (size_t)16 * 1024 * 1024);     // @16MB, 64MB
    float* pML = (float*)((char*)d_ws + (size_t)80 * 1024 * 1024);     // @80MB, 1MB
    int*   dn  = (int*)  ((char*)d_ws + (size_t)81 * 1024 * 1024);     // @81MB, 1KB
    hipMemsetAsync(dn, 0, 1024, stream);   // zero done[] each launch (capture-safe)
    hipLaunchKernelGGL(prepack, dim3(512), dim3(256), 0, stream, k, v, wk, wvv);
    hipLaunchKernelGGL(flash_chunk3, dim3(1024), dim3(512), 0, stream,
                       q, vl, wk, wvv, pO, pML, dn, out);
  } else {
    hipLaunchKernelGGL(flash_fwd_fb, dim3(256), dim3(1024), 0, stream, q, k, v, vl, out);
  }
}

// Round 12
// 274.672 us; speedup vs baseline: 1.5420x; 1.5420x over previous
//
#include <hip/hip_runtime.h>

typedef unsigned short u16;
typedef __bf16 bf16x8 __attribute__((ext_vector_type(8)));
typedef float f32x4 __attribute__((ext_vector_type(4)));

union B8 { uint4 u; bf16x8 v; };
union U8 { u16 s[8]; uint4 u; };

#define NQ 2048
#define NK 2048
#define ND 128

template<int C>
__device__ __forceinline__ float dppf(float x) {
  int v = __builtin_bit_cast(int, x);
  int r = __builtin_amdgcn_update_dpp(v, v, C, 0xF, 0xF, true);
  return __builtin_bit_cast(float, r);
}
__device__ __forceinline__ float rowmax16(float x) {
  x = fmaxf(x, dppf<0xB1>(x));   // quad_perm xor1
  x = fmaxf(x, dppf<0x4E>(x));   // quad_perm xor2
  x = fmaxf(x, dppf<0x141>(x));  // row_half_mirror
  x = fmaxf(x, dppf<0x140>(x));  // row_mirror
  return x;
}
__device__ __forceinline__ float rowsum16(float x) {
  x += dppf<0xB1>(x);
  x += dppf<0x4E>(x);
  x += dppf<0x141>(x);
  x += dppf<0x140>(x);
  return x;
}

__device__ __forceinline__ bf16x8 cvt8(float4 a, float4 b) {
  bf16x8 r;
  r[0] = (__bf16)a.x; r[1] = (__bf16)a.y; r[2] = (__bf16)a.z; r[3] = (__bf16)a.w;
  r[4] = (__bf16)b.x; r[5] = (__bf16)b.y; r[6] = (__bf16)b.z; r[7] = (__bf16)b.w;
  return r;
}

// async 16B/lane global->LDS copy; HW writes LDS at wave-uniform base + lane*16.
__device__ __forceinline__ void async16(const u16* g, u16* l) {
  __builtin_amdgcn_global_load_lds(
      (const __attribute__((address_space(1))) unsigned int*)g,
      (__attribute__((address_space(3))) unsigned int*)l, 16, 0, 0);
}

constexpr float CEXP = 0.08838834764831845f * 1.44269504088896340f; // log2e/sqrt(128)

// ---------- Prepass: fp32 K/V -> bf16 tile images in workspace (verified r6) ----------
//   K: (row,g8) at row*128 + ((g8 ^ (row&15))<<3)             [8192 u16 = 16 KB]
//   V (d-major): (d,kv) at d*64 + (((kv>>3)^(d&7))<<3)+(kv&7) [8192 u16 = 16 KB]
__global__ __launch_bounds__(256)
void prepack(const float* __restrict__ kg, const float* __restrict__ vg,
             u16* __restrict__ wk, u16* __restrict__ wvp)
{
  __shared__ __align__(16) u16 sVp[8192];
  const int bt  = blockIdx.x;             // 0..511 = b*32 + t
  const int tid = threadIdx.x;
  const int srow = tid >> 2, scq = tid & 3;
  const size_t rowoff = (size_t)((bt >> 5) * NK + (bt & 31) * 64 + srow) * ND + scq * 32;

  u16* kimg = wk + (size_t)bt * 8192;
  {
    const float* src = kg + rowoff;
    #pragma unroll
    for (int c = 0; c < 4; ++c) {
      B8 tt; tt.v = cvt8(*(const float4*)(src + c * 8), *(const float4*)(src + c * 8 + 4));
      *(uint4*)(&kimg[srow * 128 + (((scq * 4 + c) ^ (srow & 15)) << 3)]) = tt.u;
    }
  }
  {
    const float* src = vg + rowoff;
    #pragma unroll
    for (int c = 0; c < 4; ++c) {
      B8 x; x.v = cvt8(*(const float4*)(src + c * 8), *(const float4*)(src + c * 8 + 4));
      U8 tt; tt.u = x.u;
      #pragma unroll
      for (int j = 0; j < 8; ++j) {
        int d = scq * 32 + c * 8 + j;
        sVp[d * 64 + (((srow >> 3) ^ j) << 3) + (srow & 7)] = tt.s[j];
      }
    }
  }
  __syncthreads();
  u16* vimg = wvp + (size_t)bt * 8192;
  const uint4* s4 = (const uint4*)sVp;
  uint4* d4 = (uint4*)vimg;
  #pragma unroll
  for (int k = 0; k < 4; ++k) d4[tid + 256 * k] = s4[tid + 256 * k];
}

// ---------- flash_chunk: task = (b, 128-row q-tile, 512-row KV chunk) ----------
// r8-EXACT config (measured 66us, the session's load-balanced optimum):
// 512 threads = 8 q-waves x 16 rows, double-buffered K/V via global_load_lds,
// LDS 80KB -> 2 blocks/CU, launch_bounds(512,4). NO setprio (r11: starves the
// co-resident block). NO in-kernel fence-merge (r10/r11: per-block threadfence
// = per-block L2 writeback on non-coherent XCD L2s, catastrophic).
// Deltas vs r8: nc==1 direct-store fast path; T13 defer-max (skip O-rescale
// when no row max grows > m+8; P bounded by 2^1.02, bf16-safe).
__global__ __launch_bounds__(512, 4)
void flash_chunk(const float* __restrict__ qg, const int* __restrict__ vlg,
                 const u16* __restrict__ wk, const u16* __restrict__ wvp,
                 float* __restrict__ pO, float* __restrict__ pML,
                 float* __restrict__ og)
{
  __shared__ __align__(16) u16 sK[2][8192];   // 32 KB
  __shared__ __align__(16) u16 sV[2][8192];   // 32 KB
  __shared__ __align__(16) u16 sP[8][1024];   // 16 KB

  const int tid  = threadIdx.x;
  const int lane = tid & 63;
  const int wv   = tid >> 6;     // q-wave 0..7 (16 rows each)
  const int n    = lane & 15;
  const int quad = lane >> 4;

  const int bi   = blockIdx.x;   // 1024 blocks
  // XCD-swizzle: XCD x (= bi&7) serves batches {2x,2x+1} -> image L2 locality
  const int b    = ((bi & 7) << 1) | ((bi >> 3) & 1);
  const int qt   = (bi >> 4) & 15;
  const int ck   = bi >> 8;      // KV chunk 0..3 (8 tiles = 512 rows each)

  const int vl = vlg[b];
  const int nt = (vl + 63) >> 6;
  const int t0 = ck * 8;
  if (t0 >= nt) return;          // dead chunk: uniform exit, no barriers executed
  const int t1 = (t0 + 8 < nt) ? (t0 + 8) : nt;
  const int nc = (nt + 7) >> 3;  // live chunks for this (b,qt): 1..4

  const int qrow0 = qt * 128 + wv * 16;

  // Q fragments (A-layout: A[m=lane&15][k=quad*8+j])
  bf16x8 qf[4];
  #pragma unroll
  for (int c = 0; c < 4; ++c) {
    const float* qp = qg + (size_t)(b * NQ + qrow0 + n) * ND + c * 32 + quad * 8;
    qf[c] = cvt8(*(const float4*)qp, *(const float4*)(qp + 4));
  }

  f32x4 O[8];
  float mst[4], lst[4];
  #pragma unroll
  for (int f = 0; f < 8; ++f) O[f] = (f32x4){0.f, 0.f, 0.f, 0.f};
  #pragma unroll
  for (int r = 0; r < 4; ++r) { mst[r] = -__builtin_inff(); lst[r] = 0.f; }

  // Staging: 8 waves each async-copy their 1024-u16 slice of the K and V images.
  #define STAGE(t, buf)                                                        \
    do {                                                                       \
      const size_t io_ = (size_t)(b * 32 + (t)) * 8192 + wv * 1024;            \
      const u16* gk_ = wk  + io_ + lane * 8;                                   \
      const u16* gv_ = wvp + io_ + lane * 8;                                   \
      u16* lk_ = sK[(buf)] + wv * 1024 + lane * 8;                             \
      u16* lv_ = sV[(buf)] + wv * 1024 + lane * 8;                             \
      async16(gk_,       lk_);                                                 \
      async16(gk_ + 512, lk_ + 512);                                           \
      async16(gv_,       lv_);                                                 \
      async16(gv_ + 512, lv_ + 512);                                           \
    } while (0)

  u16* const Pw = sP[wv];

  STAGE(t0, 0);

  for (int t = t0; t < t1; ++t) {
    __syncthreads();                 // vmcnt(0) drain => buf((t-t0)&1) ready
    if (t + 1 < t1) STAGE(t + 1, (t - t0 + 1) & 1);

    const u16* Kg = sK[(t - t0) & 1];
    const u16* Vg = sV[(t - t0) & 1];

    // ---- S = Q * K^T  (16 MFMAs, 16 b128 reads) ----
    f32x4 S[4];
    #pragma unroll
    for (int jn = 0; jn < 4; ++jn) S[jn] = (f32x4){0.f, 0.f, 0.f, 0.f};
    #pragma unroll
    for (int c = 0; c < 4; ++c)
      #pragma unroll
      for (int jn = 0; jn < 4; ++jn) {
        B8 bb;   // B-frag: K[col=jn*16+n][d=c*32+quad*8+j]
        bb.u = *(const uint4*)(&Kg[(jn * 16 + n) * 128 + (((c * 4 + quad) ^ n) << 3)]);
        S[jn] = __builtin_amdgcn_mfma_f32_16x16x32_bf16(qf[c], bb.v, S[jn], 0, 0, 0);
      }

    // ---- mask tail columns (kv >= vl) ----
    if (t * 64 + 64 > vl) {
      #pragma unroll
      for (int jn = 0; jn < 4; ++jn) {
        const bool msk = (t * 64 + jn * 16 + n) >= vl;
        #pragma unroll
        for (int r = 0; r < 4; ++r)
          S[jn][r] = msk ? -1e30f : S[jn][r];
      }
    }

    // ---- online softmax (4 independent row-chains) + T13 defer-max ----
    float mx[4];
    #pragma unroll
    for (int r = 0; r < 4; ++r) {
      float m0 = fmaxf(fmaxf(S[0][r], S[1][r]), fmaxf(S[2][r], S[3][r]));
      mx[r] = rowmax16(m0);
    }
    const unsigned long long needre =
        __ballot(mx[0] > mst[0] + 8.f || mx[1] > mst[1] + 8.f ||
                 mx[2] > mst[2] + 8.f || mx[3] > mst[3] + 8.f);
    if (needre) {
      // full rescale path (r8-exact)
      float al[4];
      #pragma unroll
      for (int r = 0; r < 4; ++r) {
        float mnew = fmaxf(mst[r], mx[r]);
        float a = __builtin_exp2f((mst[r] - mnew) * CEXP);
        mst[r] = mnew;
        float ssum = 0.f;
        #pragma unroll
        for (int jn = 0; jn < 4; ++jn) {
          float p = __builtin_exp2f((S[jn][r] - mnew) * CEXP);
          S[jn][r] = p;
          ssum += p;
        }
        ssum = rowsum16(ssum);
        lst[r] = lst[r] * a + ssum;
        al[r] = a;
      }
      #pragma unroll
      for (int f = 0; f < 8; ++f) {
        O[f][0] *= al[0]; O[f][1] *= al[1]; O[f][2] *= al[2]; O[f][3] *= al[3];
      }
    } else {
      // deferred: keep m_old; P <= 2^1.02; no O-rescale, no a-chain
      #pragma unroll
      for (int r = 0; r < 4; ++r) {
        float ssum = 0.f;
        #pragma unroll
        for (int jn = 0; jn < 4; ++jn) {
          float p = __builtin_exp2f((S[jn][r] - mst[r]) * CEXP);
          S[jn][r] = p;
          ssum += p;
        }
        lst[r] += rowsum16(ssum);
      }
    }

    // P (C-layout) -> per-wave LDS; same-wave DS order guarantees RAW
    #pragma unroll
    for (int jn = 0; jn < 4; ++jn)
      #pragma unroll
      for (int r = 0; r < 4; ++r) {
        int row = quad * 4 + r;
        __bf16 h = (__bf16)S[jn][r];
        Pw[row * 64 + (((jn * 2 + (n >> 3)) ^ (row & 7)) << 3) + (n & 7)]
            = __builtin_bit_cast(u16, h);
      }

    // ---- O += P * V  (16 MFMAs, 2+16 b128 reads) ----
    #pragma unroll
    for (int kc = 0; kc < 2; ++kc) {
      B8 ta;   // A-frag: P[m=n][k=kc*32+quad*8+j]
      ta.u = *(const uint4*)(&Pw[n * 64 + (((kc * 4 + quad) ^ (n & 7)) << 3)]);
      bf16x8 af = ta.v;
      #pragma unroll
      for (int f = 0; f < 8; ++f) {
        int d = f * 16 + n;                 // d&7 == n&7
        B8 bb;   // B-frag: V[k=kv][n=d] from d-major sV
        bb.u = *(const uint4*)(&Vg[d * 64 + (((kc * 4 + quad) ^ (n & 7)) << 3)]);
        O[f] = __builtin_amdgcn_mfma_f32_16x16x32_bf16(af, bb.v, O[f], 0, 0, 0);
      }
    }
  }
  #undef STAGE

  // ---- epilogue ----
  if (nc == 1) {
    // single live chunk (vl <= 512): normalize in-register, store directly
    #pragma unroll
    for (int r = 0; r < 4; ++r) {
      const float rl = 1.0f / lst[r];
      const int qrow = qrow0 + quad * 4 + r;
      float* op = og + (size_t)(b * NQ + qrow) * ND + n;
      #pragma unroll
      for (int f = 0; f < 8; ++f)
        op[f * 16] = O[f][r] * rl;
    }
    return;
  }

  // write unnormalized partial O + (m,l)  (r8-verified layout)
  const size_t ti = (size_t)((b * 16 + qt) * 4 + ck);
  float* po = pO + ti * 16384;
  #pragma unroll
  for (int f = 0; f < 8; ++f)
    #pragma unroll
    for (int r = 0; r < 4; ++r)
      po[(wv * 16 + quad * 4 + r) * 128 + f * 16 + n] = O[f][r];
  if (n == 0) {
    float* ps = pML + ti * 256;
    #pragma unroll
    for (int r = 0; r < 4; ++r) {
      const int row = wv * 16 + quad * 4 + r;
      ps[row * 2]     = mst[r];
      ps[row * 2 + 1] = lst[r];
    }
  }
}

// ---------- merge_chunks: combine 2..4 chunk partials per (b, qt) ----------
// nc==1 tasks were stored directly by flash_chunk -> early uniform exit.
__global__ __launch_bounds__(256)
void merge_chunks(const int* __restrict__ vlg, const float* __restrict__ pO,
                  const float* __restrict__ pML, float* __restrict__ og)
{
  __shared__ float w[128][4];
  const int tid = threadIdx.x;
  const int bi  = blockIdx.x;          // 256 blocks
  const int b   = ((bi & 7) << 1) | ((bi >> 3) & 1);
  const int qt  = bi >> 4;

  const int vl = vlg[b];
  const int nt = (vl + 63) >> 6;
  const int nc = (nt + 7) >> 3;        // live chunks 1..4
  if (nc == 1) return;                 // flash_chunk stored og directly
  const size_t ti0 = (size_t)(b * 16 + qt) * 4;

  if (tid < 128) {
    const int row = tid;
    float m[4], l[4];
    float mx = -__builtin_inff();
    for (int c = 0; c < nc; ++c) {
      m[c] = pML[(ti0 + c) * 256 + row * 2];
      l[c] = pML[(ti0 + c) * 256 + row * 2 + 1];
      mx = fmaxf(mx, m[c]);
    }
    float L = 0.f;
    float a[4];
    for (int c = 0; c < nc; ++c) {
      a[c] = __builtin_exp2f((m[c] - mx) * CEXP);
      L += l[c] * a[c];
    }
    const float inv = 1.0f / L;
    #pragma unroll
    for (int c = 0; c < 4; ++c)
      w[row][c] = (c < nc) ? a[c] * inv : 0.f;
  }
  __syncthreads();

  const float4* p4 = (const float4*)(pO + ti0 * 16384);
  float4* o4 = (float4*)(og + (size_t)(b * NQ + qt * 128) * ND);
  #pragma unroll
  for (int it = 0; it < 16; ++it) {
    const int gi  = it * 256 + tid;    // float4 index 0..4095
    const int row = gi >> 5;           // 32 float4 per row
    float4 acc = {0.f, 0.f, 0.f, 0.f};
    for (int c = 0; c < nc; ++c) {
      const float4 x = p4[c * 4096 + gi];
      const float s = w[row][c];
      acc.x += x.x * s; acc.y += x.y * s; acc.z += x.z * s; acc.w += x.w * s;
    }
    o4[gi] = acc;
  }
}

// ---------- Fallback (ws < 81MB): reg-staging kernel, verified r6 ----------
__global__ __launch_bounds__(1024)
void flash_fwd_fb(const float* __restrict__ qg, const float* __restrict__ kg,
                  const float* __restrict__ vg, const int* __restrict__ vlg,
                  float* __restrict__ og)
{
  __shared__ __align__(16) u16 sK[2][64 * 128];
  __shared__ __align__(16) u16 sV[2][64 * 128];
  __shared__ __align__(16) u16 sP[16][16 * 64];

  const int tid  = threadIdx.x;
  const int lane = tid & 63;
  const int wv   = tid >> 6;
  const int qw   = wv & 7;
  const int grp  = wv >> 3;
  const int n    = lane & 15;
  const int quad = lane >> 4;

  const int bi = blockIdx.x;
  const int b  = ((bi & 7) << 1) | ((bi >> 3) & 1);
  const int qt = bi >> 4;

  const int vl = vlg[b];
  const int nt = (vl + 63) >> 6;
  const int qrow0 = qt * 128 + qw * 16;

  bf16x8 qf[4];
  #pragma unroll
  for (int c = 0; c < 4; ++c) {
    const float* qp = qg + (size_t)(b * NQ + qrow0 + n) * ND + c * 32 + quad * 8;
    qf[c] = cvt8(*(const float4*)qp, *(const float4*)(qp + 4));
  }

  f32x4 O[8];
  float mst[4], lst[4];
  #pragma unroll
  for (int f = 0; f < 8; ++f) O[f] = (f32x4){0.f, 0.f, 0.f, 0.f};
  #pragma unroll
  for (int r = 0; r < 4; ++r) { mst[r] = -__builtin_inff(); lst[r] = 0.f; }

  const float* kb = kg + (size_t)(b * NK) * ND;
  const float* vb = vg + (size_t)(b * NK) * ND;
  const int stid = tid & 511;
  const int srow = stid >> 3, sc8 = stid & 7;
  bf16x8 kreg[2], vreg[2];

  auto kload = [&](int t) {
    const float* src = kb + (size_t)(t * 64 + srow) * ND + sc8 * 16;
    #pragma unroll
    for (int c = 0; c < 2; ++c)
      kreg[c] = cvt8(*(const float4*)(src + c * 8), *(const float4*)(src + c * 8 + 4));
  };
  auto kstore = [&]() {
    #pragma unroll
    for (int c = 0; c < 2; ++c) {
      B8 tt; tt.v = kreg[c];
      *(uint4*)(&sK[grp][srow * 128 + (((sc8 * 2 + c) ^ (srow & 15)) << 3)]) = tt.u;
    }
  };
  auto vload = [&](int t) {
    const float* src = vb + (size_t)(t * 64 + srow) * ND + sc8 * 16;
    #pragma unroll
    for (int c = 0; c < 2; ++c)
      vreg[c] = cvt8(*(const float4*)(src + c * 8), *(const float4*)(src + c * 8 + 4));
  };
  auto vstore = [&]() {
    #pragma unroll
    for (int c = 0; c < 2; ++c) {
      B8 x; x.v = vreg[c];
      U8 tt; tt.u = x.u;
      #pragma unroll
      for (int j = 0; j < 8; ++j) {
        int d = sc8 * 16 + c * 8 + j;
        sV[grp][d * 64 + (((srow >> 3) ^ j) << 3) + (srow & 7)] = tt.s[j];
      }
    }
  };

  if (grp < nt) { kload(grp); vload(grp); kstore(); vstore(); }

  u16* Pw = sP[wv];
  const u16* Kg = sK[grp];
  const u16* Vg = sV[grp];

  const int NS = (nt + 1) >> 1;
  for (int i = 0; i < NS; ++i) {
    __syncthreads();
    const int t  = 2 * i + grp;
    const int tn = t + 2;
    if (tn < nt) { kload(tn); vload(tn); }

    if (t < nt) {
      f32x4 S[4];
      #pragma unroll
      for (int jn = 0; jn < 4; ++jn) S[jn] = (f32x4){0.f, 0.f, 0.f, 0.f};
      #pragma unroll
      for (int c = 0; c < 4; ++c)
        #pragma unroll
        for (int jn = 0; jn < 4; ++jn) {
          B8 bb;
          bb.u = *(const uint4*)(&Kg[(jn * 16 + n) * 128 + (((c * 4 + quad) ^ n) << 3)]);
          S[jn] = __builtin_amdgcn_mfma_f32_16x16x32_bf16(qf[c], bb.v, S[jn], 0, 0, 0);
        }
      if (t * 64 + 64 > vl) {
        #pragma unroll
        for (int jn = 0; jn < 4; ++jn) {
          const bool msk = (t * 64 + jn * 16 + n) >= vl;
          #pragma unroll
          for (int r = 0; r < 4; ++r)
            S[jn][r] = msk ? -1e30f : S[jn][r];
        }
      }
      float al[4];
      #pragma unroll
      for (int r = 0; r < 4; ++r) {
        float mx = fmaxf(fmaxf(S[0][r], S[1][r]), fmaxf(S[2][r], S[3][r]));
        mx = rowmax16(mx);
        float mnew = fmaxf(mst[r], mx);
        float a = __builtin_exp2f((mst[r] - mnew) * CEXP);
        mst[r] = mnew;
        float ssum = 0.f;
        #pragma unroll
        for (int jn = 0; jn < 4; ++jn) {
          float p = __builtin_exp2f((S[jn][r] - mnew) * CEXP);
          S[jn][r] = p;
          ssum += p;
        }
        ssum = rowsum16(ssum);
        lst[r] = lst[r] * a + ssum;
        al[r] = a;
      }
      #pragma unroll
      for (int f = 0; f < 8; ++f) {
        O[f][0] *= al[0]; O[f][1] *= al[1]; O[f][2] *= al[2]; O[f][3] *= al[3];
      }
      #pragma unroll
      for (int jn = 0; jn < 4; ++jn)
        #pragma unroll
        for (int r = 0; r < 4; ++r) {
          int row = quad * 4 + r;
          __bf16 h = (__bf16)S[jn][r];
          Pw[row * 64 + (((jn * 2 + (n >> 3)) ^ (row & 7)) << 3) + (n & 7)]
              = __builtin_bit_cast(u16, h);
        }
      #pragma unroll
      for (int kc = 0; kc < 2; ++kc) {
        B8 ta;
        ta.u = *(const uint4*)(&Pw[n * 64 + (((kc * 4 + quad) ^ (n & 7)) << 3)]);
        bf16x8 af = ta.v;
        #pragma unroll
        for (int f = 0; f < 8; ++f) {
          int d = f * 16 + n;
          B8 bb;
          bb.u = *(const uint4*)(&Vg[d * 64 + (((kc * 4 + quad) ^ (n & 7)) << 3)]);
          O[f] = __builtin_amdgcn_mfma_f32_16x16x32_bf16(af, bb.v, O[f], 0, 0, 0);
        }
      }
    }
    __syncthreads();
    if (tn < nt) { kstore(); vstore(); }
  }

  if (grp == 1) {
    float* ob = ((qw < 4) ? (float*)sK : (float*)sV) + (qw & 3) * 2048 + lane * 32;
    #pragma unroll
    for (int f = 0; f < 8; ++f)
      #pragma unroll
      for (int r = 0; r < 4; ++r)
        ob[f * 4 + r] = O[f][r];
    float* sb = (float*)sP + qw * 512 + lane * 8;
    #pragma unroll
    for (int r = 0; r < 4; ++r) { sb[r] = mst[r]; sb[4 + r] = lst[r]; }
  }
  __syncthreads();
  if (grp == 0) {
    const float* ob = ((qw < 4) ? (const float*)sK : (const float*)sV) + (qw & 3) * 2048 + lane * 32;
    const float* sb = (const float*)sP + qw * 512 + lane * 8;
    #pragma unroll
    for (int r = 0; r < 4; ++r) {
      const float m1 = sb[r], l1 = sb[4 + r];
      const float m  = fmaxf(mst[r], m1);
      const float a0 = __builtin_exp2f((mst[r] - m) * CEXP);
      const float a1 = __builtin_exp2f((m1 - m) * CEXP);
      const float rl = 1.0f / (lst[r] * a0 + l1 * a1);
      const int qrow = qrow0 + quad * 4 + r;
      float* op = og + (size_t)(b * NQ + qrow) * ND + n;
      #pragma unroll
      for (int f = 0; f < 8; ++f)
        op[f * 16] = (O[f][r] * a0 + ob[f * 4 + r] * a1) * rl;
    }
  }
}

extern "C" void kernel_launch(void* const* d_in, const int* in_sizes, int n_in,
                              void* d_out, int out_size, void* d_ws, size_t ws_size,
                              hipStream_t stream) {
  const float* q  = (const float*)d_in[0];
  const float* k  = (const float*)d_in[1];
  const float* v  = (const float*)d_in[2];
  const int*  vl  = (const int*)d_in[3];
  float* out = (float*)d_out;

  const size_t need = (size_t)81 * 1024 * 1024;   // images 16MB + pO 64MB + pML 1MB

  if (ws_size >= need) {
    u16*   wk  = (u16*)d_ws;                                           // @0,  8MB
    u16*   wvv = wk + 4194304;                                         // @8MB, 8MB
    float* pO  = (float*)((char*)d_ws + (size_t)16 * 1024 * 1024);     // @16MB, 64MB
    float* pML = (float*)((char*)d_ws + (size_t)80 * 1024 * 1024);     // @80MB, 1MB
    hipLaunchKernelGGL(prepack, dim3(512), dim3(256), 0, stream, k, v, wk, wvv);
    hipLaunchKernelGGL(flash_chunk, dim3(1024), dim3(512), 0, stream,
                       q, vl, wk, wvv, pO, pML, out);
    hipLaunchKernelGGL(merge_chunks, dim3(256), dim3(256), 0, stream,
                       vl, pO, pML, out);
  } else {
    hipLaunchKernelGGL(flash_fwd_fb, dim3(256), dim3(1024), 0, stream, q, k, v, vl, out);
  }
}

// Round 13
// 172.587 us; speedup vs baseline: 2.4541x; 1.5915x over previous
//
#include <hip/hip_runtime.h>

typedef unsigned short u16;
typedef __bf16 bf16x8 __attribute__((ext_vector_type(8)));
typedef float f32x4 __attribute__((ext_vector_type(4)));

union B8 { uint4 u; bf16x8 v; };
union U8 { u16 s[8]; uint4 u; };

#define NQ 2048
#define NK 2048
#define ND 128

template<int C>
__device__ __forceinline__ float dppf(float x) {
  int v = __builtin_bit_cast(int, x);
  int r = __builtin_amdgcn_update_dpp(v, v, C, 0xF, 0xF, true);
  return __builtin_bit_cast(float, r);
}
__device__ __forceinline__ float rowmax16(float x) {
  x = fmaxf(x, dppf<0xB1>(x));   // quad_perm xor1
  x = fmaxf(x, dppf<0x4E>(x));   // quad_perm xor2
  x = fmaxf(x, dppf<0x141>(x));  // row_half_mirror
  x = fmaxf(x, dppf<0x140>(x));  // row_mirror
  return x;
}
__device__ __forceinline__ float rowsum16(float x) {
  x += dppf<0xB1>(x);
  x += dppf<0x4E>(x);
  x += dppf<0x141>(x);
  x += dppf<0x140>(x);
  return x;
}

__device__ __forceinline__ bf16x8 cvt8(float4 a, float4 b) {
  bf16x8 r;
  r[0] = (__bf16)a.x; r[1] = (__bf16)a.y; r[2] = (__bf16)a.z; r[3] = (__bf16)a.w;
  r[4] = (__bf16)b.x; r[5] = (__bf16)b.y; r[6] = (__bf16)b.z; r[7] = (__bf16)b.w;
  return r;
}

// async 16B/lane global->LDS copy; HW writes LDS at wave-uniform base + lane*16.
__device__ __forceinline__ void async16(const u16* g, u16* l) {
  __builtin_amdgcn_global_load_lds(
      (const __attribute__((address_space(1))) unsigned int*)g,
      (__attribute__((address_space(3))) unsigned int*)l, 16, 0, 0);
}

constexpr float CEXP = 0.08838834764831845f * 1.44269504088896340f; // log2e/sqrt(128)

// ---------- Prepass: fp32 K/V -> bf16 tile images in workspace (verified r6) ----------
//   K: (row,g8) at row*128 + ((g8 ^ (row&15))<<3)             [8192 u16 = 16 KB]
//   V (d-major): (d,kv) at d*64 + (((kv>>3)^(d&7))<<3)+(kv&7) [8192 u16 = 16 KB]
__global__ __launch_bounds__(256)
void prepack(const float* __restrict__ kg, const float* __restrict__ vg,
             u16* __restrict__ wk, u16* __restrict__ wvp)
{
  __shared__ __align__(16) u16 sVp[8192];
  const int bt  = blockIdx.x;             // 0..511 = b*32 + t
  const int tid = threadIdx.x;
  const int srow = tid >> 2, scq = tid & 3;
  const size_t rowoff = (size_t)((bt >> 5) * NK + (bt & 31) * 64 + srow) * ND + scq * 32;

  u16* kimg = wk + (size_t)bt * 8192;
  {
    const float* src = kg + rowoff;
    #pragma unroll
    for (int c = 0; c < 4; ++c) {
      B8 tt; tt.v = cvt8(*(const float4*)(src + c * 8), *(const float4*)(src + c * 8 + 4));
      *(uint4*)(&kimg[srow * 128 + (((scq * 4 + c) ^ (srow & 15)) << 3)]) = tt.u;
    }
  }
  {
    const float* src = vg + rowoff;
    #pragma unroll
    for (int c = 0; c < 4; ++c) {
      B8 x; x.v = cvt8(*(const float4*)(src + c * 8), *(const float4*)(src + c * 8 + 4));
      U8 tt; tt.u = x.u;
      #pragma unroll
      for (int j = 0; j < 8; ++j) {
        int d = scq * 32 + c * 8 + j;
        sVp[d * 64 + (((srow >> 3) ^ j) << 3) + (srow & 7)] = tt.s[j];
      }
    }
  }
  __syncthreads();
  u16* vimg = wvp + (size_t)bt * 8192;
  const uint4* s4 = (const uint4*)sVp;
  uint4* d4 = (uint4*)vimg;
  #pragma unroll
  for (int k = 0; k < 4; ++k) d4[tid + 256 * k] = s4[tid + 256 * k];
}

// ---------- flash_chunk: task = (b, 128-row q-tile, 512-row KV chunk) ----------
// r8-EXACT loop (measured 66us, zero conflicts, no spills — the session's
// balanced optimum): 512 threads = 8 q-waves x 16 rows, double-buffered K/V via
// global_load_lds, LDS 80KB -> 2 blocks/CU. NO setprio (r11), NO in-kernel
// fence-merge (r10/r11), NO defer-max (r12: +8 live regs at the 64-VGPR cap ->
// ~190MB scratch spill traffic, FETCH 19->140MB). Only delta vs r8: epilogue
// nc==1 fast path (register-only, after loop -> loop regalloc untouched).
__global__ __launch_bounds__(512, 4)
void flash_chunk(const float* __restrict__ qg, const int* __restrict__ vlg,
                 const u16* __restrict__ wk, const u16* __restrict__ wvp,
                 float* __restrict__ pO, float* __restrict__ pML,
                 float* __restrict__ og)
{
  __shared__ __align__(16) u16 sK[2][8192];   // 32 KB
  __shared__ __align__(16) u16 sV[2][8192];   // 32 KB
  __shared__ __align__(16) u16 sP[8][1024];   // 16 KB

  const int tid  = threadIdx.x;
  const int lane = tid & 63;
  const int wv   = tid >> 6;     // q-wave 0..7 (16 rows each)
  const int n    = lane & 15;
  const int quad = lane >> 4;

  const int bi   = blockIdx.x;   // 1024 blocks
  // XCD-swizzle: XCD x (= bi&7) serves batches {2x,2x+1} -> image L2 locality
  const int b    = ((bi & 7) << 1) | ((bi >> 3) & 1);
  const int qt   = (bi >> 4) & 15;
  const int ck   = bi >> 8;      // KV chunk 0..3 (8 tiles = 512 rows each)

  const int vl = vlg[b];
  const int nt = (vl + 63) >> 6;
  const int t0 = ck * 8;
  if (t0 >= nt) return;          // dead chunk: uniform exit, no barriers executed
  const int t1 = (t0 + 8 < nt) ? (t0 + 8) : nt;
  const int nc = (nt + 7) >> 3;  // live chunks for this (b,qt): 1..4

  const int qrow0 = qt * 128 + wv * 16;

  // Q fragments (A-layout: A[m=lane&15][k=quad*8+j])
  bf16x8 qf[4];
  #pragma unroll
  for (int c = 0; c < 4; ++c) {
    const float* qp = qg + (size_t)(b * NQ + qrow0 + n) * ND + c * 32 + quad * 8;
    qf[c] = cvt8(*(const float4*)qp, *(const float4*)(qp + 4));
  }

  f32x4 O[8];
  float mst[4], lst[4];
  #pragma unroll
  for (int f = 0; f < 8; ++f) O[f] = (f32x4){0.f, 0.f, 0.f, 0.f};
  #pragma unroll
  for (int r = 0; r < 4; ++r) { mst[r] = -__builtin_inff(); lst[r] = 0.f; }

  // Staging: 8 waves each async-copy their 1024-u16 slice of the K and V images.
  #define STAGE(t, buf)                                                        \
    do {                                                                       \
      const size_t io_ = (size_t)(b * 32 + (t)) * 8192 + wv * 1024;            \
      const u16* gk_ = wk  + io_ + lane * 8;                                   \
      const u16* gv_ = wvp + io_ + lane * 8;                                   \
      u16* lk_ = sK[(buf)] + wv * 1024 + lane * 8;                             \
      u16* lv_ = sV[(buf)] + wv * 1024 + lane * 8;                             \
      async16(gk_,       lk_);                                                 \
      async16(gk_ + 512, lk_ + 512);                                           \
      async16(gv_,       lv_);                                                 \
      async16(gv_ + 512, lv_ + 512);                                           \
    } while (0)

  u16* const Pw = sP[wv];

  STAGE(t0, 0);

  for (int t = t0; t < t1; ++t) {
    __syncthreads();                 // vmcnt(0) drain => buf((t-t0)&1) ready
    if (t + 1 < t1) STAGE(t + 1, (t - t0 + 1) & 1);

    const u16* Kg = sK[(t - t0) & 1];
    const u16* Vg = sV[(t - t0) & 1];

    // ---- S = Q * K^T  (16 MFMAs, 16 b128 reads) ----
    f32x4 S[4];
    #pragma unroll
    for (int jn = 0; jn < 4; ++jn) S[jn] = (f32x4){0.f, 0.f, 0.f, 0.f};
    #pragma unroll
    for (int c = 0; c < 4; ++c)
      #pragma unroll
      for (int jn = 0; jn < 4; ++jn) {
        B8 bb;   // B-frag: K[col=jn*16+n][d=c*32+quad*8+j]
        bb.u = *(const uint4*)(&Kg[(jn * 16 + n) * 128 + (((c * 4 + quad) ^ n) << 3)]);
        S[jn] = __builtin_amdgcn_mfma_f32_16x16x32_bf16(qf[c], bb.v, S[jn], 0, 0, 0);
      }

    // ---- mask tail columns (kv >= vl) ----
    if (t * 64 + 64 > vl) {
      #pragma unroll
      for (int jn = 0; jn < 4; ++jn) {
        const bool msk = (t * 64 + jn * 16 + n) >= vl;
        #pragma unroll
        for (int r = 0; r < 4; ++r)
          S[jn][r] = msk ? -1e30f : S[jn][r];
      }
    }

    // ---- online softmax (4 independent row-chains), r8-exact ----
    float al[4];
    #pragma unroll
    for (int r = 0; r < 4; ++r) {
      float mx = fmaxf(fmaxf(S[0][r], S[1][r]), fmaxf(S[2][r], S[3][r]));
      mx = rowmax16(mx);
      float mnew = fmaxf(mst[r], mx);
      float a = __builtin_exp2f((mst[r] - mnew) * CEXP);
      mst[r] = mnew;
      float ssum = 0.f;
      #pragma unroll
      for (int jn = 0; jn < 4; ++jn) {
        float p = __builtin_exp2f((S[jn][r] - mnew) * CEXP);
        S[jn][r] = p;
        ssum += p;
      }
      ssum = rowsum16(ssum);
      lst[r] = lst[r] * a + ssum;
      al[r] = a;
    }
    #pragma unroll
    for (int f = 0; f < 8; ++f) {
      O[f][0] *= al[0]; O[f][1] *= al[1]; O[f][2] *= al[2]; O[f][3] *= al[3];
    }

    // P (C-layout) -> per-wave LDS; same-wave DS order guarantees RAW
    #pragma unroll
    for (int jn = 0; jn < 4; ++jn)
      #pragma unroll
      for (int r = 0; r < 4; ++r) {
        int row = quad * 4 + r;
        __bf16 h = (__bf16)S[jn][r];
        Pw[row * 64 + (((jn * 2 + (n >> 3)) ^ (row & 7)) << 3) + (n & 7)]
            = __builtin_bit_cast(u16, h);
      }

    // ---- O += P * V  (16 MFMAs, 2+16 b128 reads) ----
    #pragma unroll
    for (int kc = 0; kc < 2; ++kc) {
      B8 ta;   // A-frag: P[m=n][k=kc*32+quad*8+j]
      ta.u = *(const uint4*)(&Pw[n * 64 + (((kc * 4 + quad) ^ (n & 7)) << 3)]);
      bf16x8 af = ta.v;
      #pragma unroll
      for (int f = 0; f < 8; ++f) {
        int d = f * 16 + n;                 // d&7 == n&7
        B8 bb;   // B-frag: V[k=kv][n=d] from d-major sV
        bb.u = *(const uint4*)(&Vg[d * 64 + (((kc * 4 + quad) ^ (n & 7)) << 3)]);
        O[f] = __builtin_amdgcn_mfma_f32_16x16x32_bf16(af, bb.v, O[f], 0, 0, 0);
      }
    }
  }
  #undef STAGE

  // ---- epilogue ----
  if (nc == 1) {
    // single live chunk (vl <= 512): normalize in-register, store directly
    #pragma unroll
    for (int r = 0; r < 4; ++r) {
      const float rl = 1.0f / lst[r];
      const int qrow = qrow0 + quad * 4 + r;
      float* op = og + (size_t)(b * NQ + qrow) * ND + n;
      #pragma unroll
      for (int f = 0; f < 8; ++f)
        op[f * 16] = O[f][r] * rl;
    }
    return;
  }

  // write unnormalized partial O + (m,l)  (r8-verified layout)
  const size_t ti = (size_t)((b * 16 + qt) * 4 + ck);
  float* po = pO + ti * 16384;
  #pragma unroll
  for (int f = 0; f < 8; ++f)
    #pragma unroll
    for (int r = 0; r < 4; ++r)
      po[(wv * 16 + quad * 4 + r) * 128 + f * 16 + n] = O[f][r];
  if (n == 0) {
    float* ps = pML + ti * 256;
    #pragma unroll
    for (int r = 0; r < 4; ++r) {
      const int row = wv * 16 + quad * 4 + r;
      ps[row * 2]     = mst[r];
      ps[row * 2 + 1] = lst[r];
    }
  }
}

// ---------- merge_chunks: combine 2..4 chunk partials per (b, qt) ----------
// nc==1 tasks were stored directly by flash_chunk -> early uniform exit.
__global__ __launch_bounds__(256)
void merge_chunks(const int* __restrict__ vlg, const float* __restrict__ pO,
                  const float* __restrict__ pML, float* __restrict__ og)
{
  __shared__ float w[128][4];
  const int tid = threadIdx.x;
  const int bi  = blockIdx.x;          // 256 blocks
  const int b   = ((bi & 7) << 1) | ((bi >> 3) & 1);
  const int qt  = bi >> 4;

  const int vl = vlg[b];
  const int nt = (vl + 63) >> 6;
  const int nc = (nt + 7) >> 3;        // live chunks 1..4
  if (nc == 1) return;                 // flash_chunk stored og directly
  const size_t ti0 = (size_t)(b * 16 + qt) * 4;

  if (tid < 128) {
    const int row = tid;
    float m[4], l[4];
    float mx = -__builtin_inff();
    for (int c = 0; c < nc; ++c) {
      m[c] = pML[(ti0 + c) * 256 + row * 2];
      l[c] = pML[(ti0 + c) * 256 + row * 2 + 1];
      mx = fmaxf(mx, m[c]);
    }
    float L = 0.f;
    float a[4];
    for (int c = 0; c < nc; ++c) {
      a[c] = __builtin_exp2f((m[c] - mx) * CEXP);
      L += l[c] * a[c];
    }
    const float inv = 1.0f / L;
    #pragma unroll
    for (int c = 0; c < 4; ++c)
      w[row][c] = (c < nc) ? a[c] * inv : 0.f;
  }
  __syncthreads();

  const float4* p4 = (const float4*)(pO + ti0 * 16384);
  float4* o4 = (float4*)(og + (size_t)(b * NQ + qt * 128) * ND);
  #pragma unroll
  for (int it = 0; it < 16; ++it) {
    const int gi  = it * 256 + tid;    // float4 index 0..4095
    const int row = gi >> 5;           // 32 float4 per row
    float4 acc = {0.f, 0.f, 0.f, 0.f};
    for (int c = 0; c < nc; ++c) {
      const float4 x = p4[c * 4096 + gi];
      const float s = w[row][c];
      acc.x += x.x * s; acc.y += x.y * s; acc.z += x.z * s; acc.w += x.w * s;
    }
    o4[gi] = acc;
  }
}

// ---------- Fallback (ws < 81MB): reg-staging kernel, verified r6 ----------
__global__ __launch_bounds__(1024)
void flash_fwd_fb(const float* __restrict__ qg, const float* __restrict__ kg,
                  const float* __restrict__ vg, const int* __restrict__ vlg,
                  float* __restrict__ og)
{
  __shared__ __align__(16) u16 sK[2][64 * 128];
  __shared__ __align__(16) u16 sV[2][64 * 128];
  __shared__ __align__(16) u16 sP[16][16 * 64];

  const int tid  = threadIdx.x;
  const int lane = tid & 63;
  const int wv   = tid >> 6;
  const int qw   = wv & 7;
  const int grp  = wv >> 3;
  const int n    = lane & 15;
  const int quad = lane >> 4;

  const int bi = blockIdx.x;
  const int b  = ((bi & 7) << 1) | ((bi >> 3) & 1);
  const int qt = bi >> 4;

  const int vl = vlg[b];
  const int nt = (vl + 63) >> 6;
  const int qrow0 = qt * 128 + qw * 16;

  bf16x8 qf[4];
  #pragma unroll
  for (int c = 0; c < 4; ++c) {
    const float* qp = qg + (size_t)(b * NQ + qrow0 + n) * ND + c * 32 + quad * 8;
    qf[c] = cvt8(*(const float4*)qp, *(const float4*)(qp + 4));
  }

  f32x4 O[8];
  float mst[4], lst[4];
  #pragma unroll
  for (int f = 0; f < 8; ++f) O[f] = (f32x4){0.f, 0.f, 0.f, 0.f};
  #pragma unroll
  for (int r = 0; r < 4; ++r) { mst[r] = -__builtin_inff(); lst[r] = 0.f; }

  const float* kb = kg + (size_t)(b * NK) * ND;
  const float* vb = vg + (size_t)(b * NK) * ND;
  const int stid = tid & 511;
  const int srow = stid >> 3, sc8 = stid & 7;
  bf16x8 kreg[2], vreg[2];

  auto kload = [&](int t) {
    const float* src = kb + (size_t)(t * 64 + srow) * ND + sc8 * 16;
    #pragma unroll
    for (int c = 0; c < 2; ++c)
      kreg[c] = cvt8(*(const float4*)(src + c * 8), *(const float4*)(src + c * 8 + 4));
  };
  auto kstore = [&]() {
    #pragma unroll
    for (int c = 0; c < 2; ++c) {
      B8 tt; tt.v = kreg[c];
      *(uint4*)(&sK[grp][srow * 128 + (((sc8 * 2 + c) ^ (srow & 15)) << 3)]) = tt.u;
    }
  };
  auto vload = [&](int t) {
    const float* src = vb + (size_t)(t * 64 + srow) * ND + sc8 * 16;
    #pragma unroll
    for (int c = 0; c < 2; ++c)
      vreg[c] = cvt8(*(const float4*)(src + c * 8), *(const float4*)(src + c * 8 + 4));
  };
  auto vstore = [&]() {
    #pragma unroll
    for (int c = 0; c < 2; ++c) {
      B8 x; x.v = vreg[c];
      U8 tt; tt.u = x.u;
      #pragma unroll
      for (int j = 0; j < 8; ++j) {
        int d = sc8 * 16 + c * 8 + j;
        sV[grp][d * 64 + (((srow >> 3) ^ j) << 3) + (srow & 7)] = tt.s[j];
      }
    }
  };

  if (grp < nt) { kload(grp); vload(grp); kstore(); vstore(); }

  u16* Pw = sP[wv];
  const u16* Kg = sK[grp];
  const u16* Vg = sV[grp];

  const int NS = (nt + 1) >> 1;
  for (int i = 0; i < NS; ++i) {
    __syncthreads();
    const int t  = 2 * i + grp;
    const int tn = t + 2;
    if (tn < nt) { kload(tn); vload(tn); }

    if (t < nt) {
      f32x4 S[4];
      #pragma unroll
      for (int jn = 0; jn < 4; ++jn) S[jn] = (f32x4){0.f, 0.f, 0.f, 0.f};
      #pragma unroll
      for (int c = 0; c < 4; ++c)
        #pragma unroll
        for (int jn = 0; jn < 4; ++jn) {
          B8 bb;
          bb.u = *(const uint4*)(&Kg[(jn * 16 + n) * 128 + (((c * 4 + quad) ^ n) << 3)]);
          S[jn] = __builtin_amdgcn_mfma_f32_16x16x32_bf16(qf[c], bb.v, S[jn], 0, 0, 0);
        }
      if (t * 64 + 64 > vl) {
        #pragma unroll
        for (int jn = 0; jn < 4; ++jn) {
          const bool msk = (t * 64 + jn * 16 + n) >= vl;
          #pragma unroll
          for (int r = 0; r < 4; ++r)
            S[jn][r] = msk ? -1e30f : S[jn][r];
        }
      }
      float al[4];
      #pragma unroll
      for (int r = 0; r < 4; ++r) {
        float mx = fmaxf(fmaxf(S[0][r], S[1][r]), fmaxf(S[2][r], S[3][r]));
        mx = rowmax16(mx);
        float mnew = fmaxf(mst[r], mx);
        float a = __builtin_exp2f((mst[r] - mnew) * CEXP);
        mst[r] = mnew;
        float ssum = 0.f;
        #pragma unroll
        for (int jn = 0; jn < 4; ++jn) {
          float p = __builtin_exp2f((S[jn][r] - mnew) * CEXP);
          S[jn][r] = p;
          ssum += p;
        }
        ssum = rowsum16(ssum);
        lst[r] = lst[r] * a + ssum;
        al[r] = a;
      }
      #pragma unroll
      for (int f = 0; f < 8; ++f) {
        O[f][0] *= al[0]; O[f][1] *= al[1]; O[f][2] *= al[2]; O[f][3] *= al[3];
      }
      #pragma unroll
      for (int jn = 0; jn < 4; ++jn)
        #pragma unroll
        for (int r = 0; r < 4; ++r) {
          int row = quad * 4 + r;
          __bf16 h = (__bf16)S[jn][r];
          Pw[row * 64 + (((jn * 2 + (n >> 3)) ^ (row & 7)) << 3) + (n & 7)]
              = __builtin_bit_cast(u16, h);
        }
      #pragma unroll
      for (int kc = 0; kc < 2; ++kc) {
        B8 ta;
        ta.u = *(const uint4*)(&Pw[n * 64 + (((kc * 4 + quad) ^ (n & 7)) << 3)]);
        bf16x8 af = ta.v;
        #pragma unroll
        for (int f = 0; f < 8; ++f) {
          int d = f * 16 + n;
          B8 bb;
          bb.u = *(const uint4*)(&Vg[d * 64 + (((kc * 4 + quad) ^ (n & 7)) << 3)]);
          O[f] = __builtin_amdgcn_mfma_f32_16x16x32_bf16(af, bb.v, O[f], 0, 0, 0);
        }
      }
    }
    __syncthreads();
    if (tn < nt) { kstore(); vstore(); }
  }

  if (grp == 1) {
    float* ob = ((qw < 4) ? (float*)sK : (float*)sV) + (qw & 3) * 2048 + lane * 32;
    #pragma unroll
    for (int f = 0; f < 8; ++f)
      #pragma unroll
      for (int r = 0; r < 4; ++r)
        ob[f * 4 + r] = O[f][r];
    float* sb = (float*)sP + qw * 512 + lane * 8;
    #pragma unroll
    for (int r = 0; r < 4; ++r) { sb[r] = mst[r]; sb[4 + r] = lst[r]; }
  }
  __syncthreads();
  if (grp == 0) {
    const float* ob = ((qw < 4) ? (const float*)sK : (const float*)sV) + (qw & 3) * 2048 + lane * 32;
    const float* sb = (const float*)sP + qw * 512 + lane * 8;
    #pragma unroll
    for (int r = 0; r < 4; ++r) {
      const float m1 = sb[r], l1 = sb[4 + r];
      const float m  = fmaxf(mst[r], m1);
      const float a0 = __builtin_exp2f((mst[r] - m) * CEXP);
      const float a1 = __builtin_exp2f((m1 - m) * CEXP);
      const float rl = 1.0f / (lst[r] * a0 + l1 * a1);
      const int qrow = qrow0 + quad * 4 + r;
      float* op = og + (size_t)(b * NQ + qrow) * ND + n;
      #pragma unroll
      for (int f = 0; f < 8; ++f)
        op[f * 16] = (O[f][r] * a0 + ob[f * 4 + r] * a1) * rl;
    }
  }
}

extern "C" void kernel_launch(void* const* d_in, const int* in_sizes, int n_in,
                              void* d_out, int out_size, void* d_ws, size_t ws_size,
                              hipStream_t stream) {
  const float* q  = (const float*)d_in[0];
  const float* k  = (const float*)d_in[1];
  const float* v  = (const float*)d_in[2];
  const int*  vl  = (const int*)d_in[3];
  float* out = (float*)d_out;

  const size_t need = (size_t)81 * 1024 * 1024;   // images 16MB + pO 64MB + pML 1MB

  if (ws_size >= need) {
    u16*   wk  = (u16*)d_ws;                                           // @0,  8MB
    u16*   wvv = wk + 4194304;                                         // @8MB, 8MB
    float* pO  = (float*)((char*)d_ws + (size_t)16 * 1024 * 1024);     // @16MB, 64MB
    float* pML = (float*)((char*)d_ws + (size_t)80 * 1024 * 1024);     // @80MB, 1MB
    hipLaunchKernelGGL(prepack, dim3(512), dim3(256), 0, stream, k, v, wk, wvv);
    hipLaunchKernelGGL(flash_chunk, dim3(1024), dim3(512), 0, stream,
                       q, vl, wk, wvv, pO, pML, out);
    hipLaunchKernelGGL(merge_chunks, dim3(256), dim3(256), 0, stream,
                       vl, pO, pML, out);
  } else {
    hipLaunchKernelGGL(flash_fwd_fb, dim3(256), dim3(1024), 0, stream, q, k, v, vl, out);
  }
}